// Round 5
// baseline (484.174 us; speedup 1.0000x reference)
//
#include <hip/hip_runtime.h>
#include <hip/hip_bf16.h>

typedef _Float16 f16;
typedef _Float16 f16x8 __attribute__((ext_vector_type(8)));
typedef _Float16 f16x4 __attribute__((ext_vector_type(4)));
typedef float f32x4 __attribute__((ext_vector_type(4)));

// ---------------- ws layout (bytes) ----------------
#define P_OFF   0
#define W1T_OFF 14745600
#define W2T_OFF 15007744

// ---------------- k_prep: transpose + f32->f16 weights ----------------
__global__ __launch_bounds__(256) void k_prep(const float* __restrict__ W1,
                                              const float* __restrict__ W2,
                                              f16* __restrict__ w1t,
                                              f16* __restrict__ w2t) {
    long id = (long)blockIdx.x * 256 + threadIdx.x;   // 0 .. 393215
    if (id < 131072) {
        int f = (int)(id >> 8), k = (int)(id & 255);
        w1t[id] = (f16)W1[k * 512 + f];               // w1t[f][k]
    } else {
        long i = id - 131072;
        int f = (int)(i >> 9), k = (int)(i & 511);
        w2t[i] = (f16)W2[k * 512 + f];                // w2t[f][k]
    }
}

// ---------------- k_prop: wave-per-batch MFMA polynomial build ----------------
__global__ __launch_bounds__(256) void k_prop(const float* __restrict__ graph,
                                              float* __restrict__ P) {
    __shared__ float MtS[4][990];
    __shared__ float dinvS[4][32];
    __shared__ f16 qhS[4][1024];
    __shared__ f16 qlS[4][1024];

    const int wv = threadIdx.x >> 6, lane = threadIdx.x & 63;
    const int lr = lane & 15, gq = lane >> 4;
    const long b = (long)blockIdx.x * 4 + wv;
    const float* g = graph + b * 4500;
    float* Mt = MtS[wv];
    float* dinv = dinvS[wv];
    f16* qh = qhS[wv];
    f16* ql = qlS[wv];

    for (int rep = 0; rep < 15; ++rep) {
        int e = rep * 64 + lane;
        if (e < 900) {
            float s = g[e] + g[900 + e] + g[1800 + e] + g[2700 + e] + g[3600 + e];
            int r = e / 30, c = e - r * 30;
            Mt[r * 33 + c] = ((s != 0.f) ? 1.f : 0.f) + ((r == c) ? 1.f : 0.f);
        }
    }
    __syncthreads();
    if (lane < 30) {
        float d = 0.f;
        #pragma unroll
        for (int r = 0; r < 30; ++r) d += Mt[r * 33 + lane];
        dinv[lane] = 1.0f / sqrtf(d);
    }
    __syncthreads();

    auto Sval = [&](int i, int j) -> float {
        if (i >= 30 || j >= 30) return 0.f;
        return dinv[i] * Mt[j * 33 + i] * dinv[j];
    };

    f16x8 sh[2], sl[2];
    #pragma unroll
    for (int mi = 0; mi < 2; ++mi)
        #pragma unroll
        for (int jj = 0; jj < 8; ++jj) {
            float v = Sval(mi * 16 + lr, gq * 8 + jj);
            f16 h = (f16)v;
            sh[mi][jj] = h;
            sl[mi][jj] = (f16)(v - (float)h);
        }

    f32x4 qd[2][2], racc[2][2];
    #pragma unroll
    for (int mi = 0; mi < 2; ++mi)
        #pragma unroll
        for (int ni = 0; ni < 2; ++ni)
            #pragma unroll
            for (int r = 0; r < 4; ++r) {
                int row = mi * 16 + gq * 4 + r, col = ni * 16 + lr;
                qd[mi][ni][r] = Sval(row, col);
                racc[mi][ni][r] = (row == col) ? 0.1f : 0.f;
            }

    float c = 0.1f;
    for (int k = 1; k <= 9; ++k) {
        c *= 0.9f;
        #pragma unroll
        for (int mi = 0; mi < 2; ++mi)
            #pragma unroll
            for (int ni = 0; ni < 2; ++ni) {
                racc[mi][ni] += c * qd[mi][ni];
                f16x4 hh, ll;
                #pragma unroll
                for (int r = 0; r < 4; ++r) {
                    float v = qd[mi][ni][r];
                    f16 h = (f16)v;
                    hh[r] = h;
                    ll[r] = (f16)(v - (float)h);
                }
                const int col = ni * 16 + lr, rowb = mi * 16 + gq * 4;
                *reinterpret_cast<f16x4*>(qh + col * 32 + rowb) = hh;
                *reinterpret_cast<f16x4*>(ql + col * 32 + rowb) = ll;
            }
        __syncthreads();
        f16x8 bh[2], bl[2];
        #pragma unroll
        for (int ni = 0; ni < 2; ++ni) {
            const int col = ni * 16 + lr;
            bh[ni] = *reinterpret_cast<const f16x8*>(qh + col * 32 + gq * 8);
            bl[ni] = *reinterpret_cast<const f16x8*>(ql + col * 32 + gq * 8);
        }
        #pragma unroll
        for (int mi = 0; mi < 2; ++mi)
            #pragma unroll
            for (int ni = 0; ni < 2; ++ni) {
                f32x4 d = {0.f, 0.f, 0.f, 0.f};
                d = __builtin_amdgcn_mfma_f32_16x16x32_f16(sh[mi], bh[ni], d, 0, 0, 0);
                d = __builtin_amdgcn_mfma_f32_16x16x32_f16(sh[mi], bl[ni], d, 0, 0, 0);
                d = __builtin_amdgcn_mfma_f32_16x16x32_f16(sl[mi], bh[ni], d, 0, 0, 0);
                qd[mi][ni] = d;
            }
        __syncthreads();
    }
    const float cf = 0.3486784401f;   // 0.9^10
    #pragma unroll
    for (int mi = 0; mi < 2; ++mi)
        #pragma unroll
        for (int ni = 0; ni < 2; ++ni)
            #pragma unroll
            for (int r = 0; r < 4; ++r) {
                int row = mi * 16 + gq * 4 + r, col = ni * 16 + lr;
                if (row < 30 && col < 30)
                    P[b * 900 + row * 30 + col] = racc[mi][ni][r] + cf * qd[mi][ni][r];
            }
}

// ---------------- k_main (persistent, TILES per block) ----------------
// grid = 256 blocks (1/CU), 512 threads = 8 waves; each tile = 4 batches (M=128).
// LDS buf alias: chunk dbuf 2x16K (GEMM1) -> xl[128][512]f16 128K -> ut[512][128]f16 128K
#define TILES 4
#define SMEM_BYTES 150528
#define PF_OFF   131072  // Pf [4][32][32] f16 = 8192
#define B1L_OFF  139264  // [512] f32
#define B2L_OFF  141312  // [512] f32
#define WLL_OFF  143360  // [512] f32
#define RED_OFF  145408  // [8][128] f32 = 4096
#define VL_OFF   149504  // [128] f32
#define ZL_OFF   150016  // [128] f32

__global__ __launch_bounds__(512, 2) void k_main(
    const float* __restrict__ real, const f16* __restrict__ w1t,
    const f16* __restrict__ w2t, const float* __restrict__ b1,
    const float* __restrict__ b2, const float* __restrict__ wl,
    const float* __restrict__ bl, const float* __restrict__ wc,
    const float* __restrict__ bc, const float* __restrict__ Pws,
    float* __restrict__ out) {
    extern __shared__ char smem[];
    char*  buf = smem;
    f16*   Pf  = (f16*)(smem + PF_OFF);
    float* b1l = (float*)(smem + B1L_OFF);
    float* b2l = (float*)(smem + B2L_OFF);
    float* wll = (float*)(smem + WLL_OFF);
    float* red = (float*)(smem + RED_OFF);
    float* vl  = (float*)(smem + VL_OFF);
    float* zl  = (float*)(smem + ZL_OFF);

    const int tid  = threadIdx.x;
    const int lane = tid & 63;
    const int wv   = tid >> 6;
    const int gq   = lane >> 4;
    const int lr   = lane & 15;
    const int blk  = blockIdx.x;         // 0..255

    // chunk staging map: thread -> (row 0..127, col-quad 0..3); 64-col chunks
    const int crow = tid >> 2;
    const int cq   = tid & 3;
    const bool cval = (crow & 31) < 30;
    const long csrc = (long)(crow >> 5) * 30 + (crow & 31);   // row within tile's 120

    auto LOADC = [&](f32x4* r, int tt, int kc2) {
        if (cval) {
            const float* p = real + ((long)(blk * TILES + tt) * 120 + csrc) * 256
                             + kc2 * 64 + cq * 16;
            r[0] = *reinterpret_cast<const f32x4*>(p);
            r[1] = *reinterpret_cast<const f32x4*>(p + 4);
            r[2] = *reinterpret_cast<const f32x4*>(p + 8);
            r[3] = *reinterpret_cast<const f32x4*>(p + 12);
        }
    };
    auto WRITEC = [&](int slot, const f32x4* r) {
        #pragma unroll
        for (int h = 0; h < 2; ++h) {
            f16x8 v;
            #pragma unroll
            for (int j = 0; j < 8; ++j)
                v[j] = cval ? (f16)r[h * 2 + (j >> 2)][j & 3] : (f16)0.f;
            *reinterpret_cast<f16x8*>(buf + slot * 16384 + crow * 128 +
                ((cq * 32 + h * 16) ^ ((crow & 7) << 4))) = v;
        }
    };

    b1l[tid] = b1[tid];
    b2l[tid] = b2[tid];
    wll[tid] = wl[tid];

    f32x4 cregA[4], cregB[4];
    LOADC(cregA, 0, 0);                  // prologue: chunk0 of tile0

    const f16* w1p = w1t + (wv * 64 + lr) * 256;
    const f16* w2p = w2t + (wv * 64 + lr) * 512;

    #pragma unroll 1
    for (int t = 0; t < TILES; ++t) {
        // ---- tile top: publish chunk0, issue chunk1, stage Pf ----
        WRITEC(0, cregA);
        LOADC(cregB, t, 1);
        #pragma unroll
        for (int s = 0; s < 8; ++s) {
            int e = tid + s * 512;
            int bb = e >> 10, idx = e & 1023, n = idx >> 5, kk = idx & 31;
            float p = (n < 30 && kk < 31 && kk < 30)
                ? Pws[((long)(blk * TILES + t) * 4 + bb) * 900 + n * 30 + kk] : 0.f;
            Pf[e] = (f16)p;
        }
        __syncthreads();                 // chunk0 + Pf + biases visible

        f32x4 acc[4][8];
        #pragma unroll
        for (int a = 0; a < 4; ++a)
            #pragma unroll
            for (int b = 0; b < 8; ++b) { f32x4 z = {0.f,0.f,0.f,0.f}; acc[a][b] = z; }

        // ======== GEMM1: D[feat][node] = W1^T @ A^T, K=256, chunk-pipelined ====
        #pragma unroll
        for (int kc2 = 0; kc2 < 4; ++kc2) {
            const int slot = kc2 & 1;
            char* sb = buf + slot * 16384;
            f16x8 wa[4], wb[4];
            #pragma unroll
            for (int mi = 0; mi < 4; ++mi) {
                wa[mi] = *reinterpret_cast<const f16x8*>(w1p + mi * 4096 + kc2 * 64 + gq * 8);
                wb[mi] = *reinterpret_cast<const f16x8*>(w1p + mi * 4096 + kc2 * 64 + 32 + gq * 8);
            }
            if (kc2 < 3) WRITEC(slot ^ 1, (kc2 & 1) ? cregA : cregB);
            if (kc2 < 2) LOADC((kc2 & 1) ? cregB : cregA, t, kc2 + 2);
            f16x8 bf[8];
            #pragma unroll
            for (int ni = 0; ni < 8; ++ni) {
                const int row = ni * 16 + lr;
                bf[ni] = *reinterpret_cast<const f16x8*>(
                    sb + row * 128 + ((gq * 16) ^ ((row & 7) << 4)));
            }
            #pragma unroll
            for (int mi = 0; mi < 4; ++mi)
                #pragma unroll
                for (int ni = 0; ni < 8; ++ni)
                    acc[mi][ni] = __builtin_amdgcn_mfma_f32_16x16x32_f16(wa[mi], bf[ni], acc[mi][ni], 0, 0, 0);
            #pragma unroll
            for (int ni = 0; ni < 8; ++ni) {
                const int row = ni * 16 + lr;
                bf[ni] = *reinterpret_cast<const f16x8*>(
                    sb + row * 128 + ((64 + gq * 16) ^ ((row & 7) << 4)));
            }
            #pragma unroll
            for (int mi = 0; mi < 4; ++mi)
                #pragma unroll
                for (int ni = 0; ni < 8; ++ni)
                    acc[mi][ni] = __builtin_amdgcn_mfma_f32_16x16x32_f16(wb[mi], bf[ni], acc[mi][ni], 0, 0, 0);
            __syncthreads();
        }

        // ---- ep1: xl[node][feat] = relu(acc + b1), (node&15)<<4 swizzle ----
        #pragma unroll
        for (int mi = 0; mi < 4; ++mi) {
            const int featb = wv * 64 + mi * 16 + gq * 4;
            float b1v[4];
            #pragma unroll
            for (int j = 0; j < 4; ++j) b1v[j] = b1l[featb + j];
            #pragma unroll
            for (int ni = 0; ni < 8; ++ni) {
                const int node = ni * 16 + lr;
                f16x4 h;
                #pragma unroll
                for (int j = 0; j < 4; ++j)
                    h[j] = (f16)fmaxf(acc[mi][ni][j] + b1v[j], 0.f);
                *reinterpret_cast<f16x4*>(
                    buf + node * 1024 + ((featb * 2) ^ ((node & 15) << 4))) = h;
            }
        }
        #pragma unroll
        for (int a = 0; a < 4; ++a)
            #pragma unroll
            for (int b = 0; b < 8; ++b) { f32x4 z = {0.f,0.f,0.f,0.f}; acc[a][b] = z; }
        __syncthreads();

        // ======== GEMM2: D[node][feat] = x @ W2, K=512, barrier-free ========
        f16x8 bfA[4], bfB[4];
        #pragma unroll
        for (int ni = 0; ni < 4; ++ni)
            bfA[ni] = *reinterpret_cast<const f16x8*>(w2p + ni * 8192 + gq * 8);
        #pragma unroll
        for (int ni = 0; ni < 4; ++ni)
            bfB[ni] = *reinterpret_cast<const f16x8*>(w2p + ni * 8192 + 32 + gq * 8);
        #pragma unroll
        for (int kc2 = 0; kc2 < 8; ++kc2) {
            {   // even kc
                const int kc = 2 * kc2;
                f16x8 af[8];
                #pragma unroll
                for (int mi = 0; mi < 8; ++mi) {
                    const int row = mi * 16 + lr;
                    af[mi] = *reinterpret_cast<const f16x8*>(
                        buf + row * 1024 + (((kc * 32 + gq * 8) * 2) ^ ((row & 15) << 4)));
                }
                #pragma unroll
                for (int mi = 0; mi < 8; ++mi)
                    #pragma unroll
                    for (int ni = 0; ni < 4; ++ni)
                        acc[ni][mi] = __builtin_amdgcn_mfma_f32_16x16x32_f16(af[mi], bfA[ni], acc[ni][mi], 0, 0, 0);
                if (kc + 2 < 16)
                    #pragma unroll
                    for (int ni = 0; ni < 4; ++ni)
                        bfA[ni] = *reinterpret_cast<const f16x8*>(w2p + ni * 8192 + (kc + 2) * 32 + gq * 8);
            }
            {   // odd kc
                const int kc = 2 * kc2 + 1;
                f16x8 af[8];
                #pragma unroll
                for (int mi = 0; mi < 8; ++mi) {
                    const int row = mi * 16 + lr;
                    af[mi] = *reinterpret_cast<const f16x8*>(
                        buf + row * 1024 + (((kc * 32 + gq * 8) * 2) ^ ((row & 15) << 4)));
                }
                #pragma unroll
                for (int mi = 0; mi < 8; ++mi)
                    #pragma unroll
                    for (int ni = 0; ni < 4; ++ni)
                        acc[ni][mi] = __builtin_amdgcn_mfma_f32_16x16x32_f16(af[mi], bfB[ni], acc[ni][mi], 0, 0, 0);
                if (kc + 2 < 16)
                    #pragma unroll
                    for (int ni = 0; ni < 4; ++ni)
                        bfB[ni] = *reinterpret_cast<const f16x8*>(w2p + ni * 8192 + (kc + 2) * 32 + gq * 8);
            }
        }
        __syncthreads();   // xl reads done; buf -> ut[512][128]

        // ---- ep2: ut[feat][node], (feat&15)<<4 swizzle; preload next chunk0 ----
        #pragma unroll
        for (int mi = 0; mi < 8; ++mi)
            #pragma unroll
            for (int ni = 0; ni < 4; ++ni) {
                const int feat  = wv * 64 + ni * 16 + lr;
                const int node0 = mi * 16 + gq * 4;
                f16x4 h;
                #pragma unroll
                for (int j = 0; j < 4; ++j) h[j] = (f16)acc[ni][mi][j];
                *reinterpret_cast<f16x4*>(
                    buf + feat * 256 + ((node0 * 2) ^ ((feat & 15) << 4))) = h;
            }
        if (t + 1 < TILES) LOADC(cregA, t + 1, 0);   // hide under phase5/tail
        __syncthreads();

        // ======== phase5: Y^T = U^T @ P^T, y=relu(+b2), v = y.wl ========
        {
            f16x8 pb[4][2];
            #pragma unroll
            for (int bb = 0; bb < 4; ++bb)
                #pragma unroll
                for (int ni = 0; ni < 2; ++ni)
                    pb[bb][ni] = *reinterpret_cast<const f16x8*>(
                        Pf + bb * 1024 + (ni * 16 + lr) * 32 + gq * 8);
            float vacc[4][2];
            #pragma unroll
            for (int bb = 0; bb < 4; ++bb)
                #pragma unroll
                for (int ni = 0; ni < 2; ++ni) vacc[bb][ni] = 0.f;
            #pragma unroll
            for (int mi = 0; mi < 4; ++mi) {
                const int featb = wv * 64 + mi * 16;
                float b2v[4], wlv[4];
                #pragma unroll
                for (int j = 0; j < 4; ++j) {
                    b2v[j] = b2l[featb + gq * 4 + j];
                    wlv[j] = wll[featb + gq * 4 + j];
                }
                f16x8 au[4];
                #pragma unroll
                for (int bb = 0; bb < 4; ++bb) {
                    const int feat = featb + lr;
                    au[bb] = *reinterpret_cast<const f16x8*>(
                        buf + feat * 256 + ((bb * 64 + gq * 16) ^ ((feat & 15) << 4)));
                }
                #pragma unroll
                for (int bb = 0; bb < 4; ++bb)
                    #pragma unroll
                    for (int ni = 0; ni < 2; ++ni) {
                        f32x4 d = {0.f,0.f,0.f,0.f};
                        d = __builtin_amdgcn_mfma_f32_16x16x32_f16(au[bb], pb[bb][ni], d, 0, 0, 0);
                        #pragma unroll
                        for (int j = 0; j < 4; ++j) {
                            float y = fmaxf(d[j] + b2v[j], 0.f);
                            vacc[bb][ni] = fmaf(y, wlv[j], vacc[bb][ni]);
                        }
                    }
            }
            #pragma unroll
            for (int bb = 0; bb < 4; ++bb)
                #pragma unroll
                for (int ni = 0; ni < 2; ++ni) {
                    float v = vacc[bb][ni];
                    v += __shfl_xor(v, 16);
                    v += __shfl_xor(v, 32);
                    if (lane < 16) red[wv * 128 + bb * 32 + ni * 16 + lr] = v;
                }
        }
        __syncthreads();
        if (tid < 128) {
            float s = 0.f;
            #pragma unroll
            for (int w = 0; w < 8; ++w) s += red[w * 128 + tid];
            vl[tid] = s;
        }
        __syncthreads();
        if (tid < 120) {
            const int bb = tid / 30, n = tid - bb * 30;
            const float* Pr = Pws + ((long)(blk * TILES + t) * 4 + bb) * 900 + n * 30;
            float z = bl[0];
            #pragma unroll
            for (int j = 0; j < 30; ++j) z = fmaf(Pr[j], vl[bb * 32 + j], z);
            zl[tid] = fmaxf(z, 0.f);
        }
        __syncthreads();
        if (tid < 16) {
            const int bb = tid >> 2, cc = tid & 3;
            float o = bc[cc];
            #pragma unroll
            for (int n = 0; n < 30; ++n) o = fmaf(zl[bb * 30 + n], wc[cc * 30 + n], o);
            out[((long)(blk * TILES + t) * 4 + bb) * 4 + cc] = o;
        }
        // no extra barrier: next tile's WRITEC targets chunk region (ut) whose
        // readers (phase5) are already fenced by the red/vl barriers above;
        // Pf readers likewise. zl readers (out) race only with global loads.
        __syncthreads();
    }
}

extern "C" void kernel_launch(void* const* d_in, const int* in_sizes, int n_in,
                              void* d_out, int out_size, void* d_ws, size_t ws_size,
                              hipStream_t stream) {
    const float* real  = (const float*)d_in[0];
    const float* graph = (const float*)d_in[2];
    const float* W1    = (const float*)d_in[3];
    const float* b1    = (const float*)d_in[4];
    const float* W2    = (const float*)d_in[5];
    const float* b2    = (const float*)d_in[6];
    const float* Wl    = (const float*)d_in[7];
    const float* bl    = (const float*)d_in[8];
    const float* Wc    = (const float*)d_in[9];
    const float* bc    = (const float*)d_in[10];
    float* out = (float*)d_out;
    char*  ws  = (char*)d_ws;

    float* Pws = (float*)(ws + P_OFF);
    f16*   w1t = (f16*)(ws + W1T_OFF);
    f16*   w2t = (f16*)(ws + W2T_OFF);

    k_prep<<<1536, 256, 0, stream>>>(W1, W2, w1t, w2t);
    k_prop<<<1024, 256, 0, stream>>>(graph, Pws);
    (void)hipFuncSetAttribute((const void*)k_main,
                              hipFuncAttributeMaxDynamicSharedMemorySize, SMEM_BYTES);
    k_main<<<256, 512, SMEM_BYTES, stream>>>(real, w1t, w2t, b1, b2, Wl, bl, Wc, bc,
                                             Pws, out);
}

// Round 6
// 184.293 us; speedup vs baseline: 2.6272x; 2.6272x over previous
//
#include <hip/hip_runtime.h>
#include <hip/hip_bf16.h>

typedef _Float16 f16;
typedef _Float16 f16x8 __attribute__((ext_vector_type(8)));
typedef _Float16 f16x4 __attribute__((ext_vector_type(4)));
typedef float f32x4 __attribute__((ext_vector_type(4)));

// ---------------- ws layout (bytes) ----------------
#define P_OFF   0
#define W1T_OFF 14745600
#define W2T_OFF 15007744

// ---------------- k_prep: transpose + f32->f16 weights ----------------
__global__ __launch_bounds__(256) void k_prep(const float* __restrict__ W1,
                                              const float* __restrict__ W2,
                                              f16* __restrict__ w1t,
                                              f16* __restrict__ w2t) {
    long id = (long)blockIdx.x * 256 + threadIdx.x;   // 0 .. 393215
    if (id < 131072) {
        int f = (int)(id >> 8), k = (int)(id & 255);
        w1t[id] = (f16)W1[k * 512 + f];               // w1t[f][k]
    } else {
        long i = id - 131072;
        int f = (int)(i >> 9), k = (int)(i & 511);
        w2t[i] = (f16)W2[k * 512 + f];                // w2t[f][k]
    }
}

// ---------------- k_prop: wave-per-batch MFMA polynomial build ----------------
__global__ __launch_bounds__(256) void k_prop(const float* __restrict__ graph,
                                              float* __restrict__ P) {
    __shared__ float MtS[4][990];
    __shared__ float dinvS[4][32];
    __shared__ f16 qhS[4][1024];
    __shared__ f16 qlS[4][1024];

    const int wv = threadIdx.x >> 6, lane = threadIdx.x & 63;
    const int lr = lane & 15, gq = lane >> 4;
    const long b = (long)blockIdx.x * 4 + wv;
    const float* g = graph + b * 4500;
    float* Mt = MtS[wv];
    float* dinv = dinvS[wv];
    f16* qh = qhS[wv];
    f16* ql = qlS[wv];

    for (int rep = 0; rep < 15; ++rep) {
        int e = rep * 64 + lane;
        if (e < 900) {
            float s = g[e] + g[900 + e] + g[1800 + e] + g[2700 + e] + g[3600 + e];
            int r = e / 30, c = e - r * 30;
            Mt[r * 33 + c] = ((s != 0.f) ? 1.f : 0.f) + ((r == c) ? 1.f : 0.f);
        }
    }
    __syncthreads();
    if (lane < 30) {
        float d = 0.f;
        #pragma unroll
        for (int r = 0; r < 30; ++r) d += Mt[r * 33 + lane];
        dinv[lane] = 1.0f / sqrtf(d);
    }
    __syncthreads();

    auto Sval = [&](int i, int j) -> float {
        if (i >= 30 || j >= 30) return 0.f;
        return dinv[i] * Mt[j * 33 + i] * dinv[j];
    };

    f16x8 sh[2], sl[2];
    #pragma unroll
    for (int mi = 0; mi < 2; ++mi)
        #pragma unroll
        for (int jj = 0; jj < 8; ++jj) {
            float v = Sval(mi * 16 + lr, gq * 8 + jj);
            f16 h = (f16)v;
            sh[mi][jj] = h;
            sl[mi][jj] = (f16)(v - (float)h);
        }

    f32x4 qd[2][2], racc[2][2];
    #pragma unroll
    for (int mi = 0; mi < 2; ++mi)
        #pragma unroll
        for (int ni = 0; ni < 2; ++ni)
            #pragma unroll
            for (int r = 0; r < 4; ++r) {
                int row = mi * 16 + gq * 4 + r, col = ni * 16 + lr;
                qd[mi][ni][r] = Sval(row, col);
                racc[mi][ni][r] = (row == col) ? 0.1f : 0.f;
            }

    float c = 0.1f;
    for (int k = 1; k <= 9; ++k) {
        c *= 0.9f;
        #pragma unroll
        for (int mi = 0; mi < 2; ++mi)
            #pragma unroll
            for (int ni = 0; ni < 2; ++ni) {
                racc[mi][ni] += c * qd[mi][ni];
                f16x4 hh, ll;
                #pragma unroll
                for (int r = 0; r < 4; ++r) {
                    float v = qd[mi][ni][r];
                    f16 h = (f16)v;
                    hh[r] = h;
                    ll[r] = (f16)(v - (float)h);
                }
                const int col = ni * 16 + lr, rowb = mi * 16 + gq * 4;
                *reinterpret_cast<f16x4*>(qh + col * 32 + rowb) = hh;
                *reinterpret_cast<f16x4*>(ql + col * 32 + rowb) = ll;
            }
        __syncthreads();
        f16x8 bh[2], bl[2];
        #pragma unroll
        for (int ni = 0; ni < 2; ++ni) {
            const int col = ni * 16 + lr;
            bh[ni] = *reinterpret_cast<const f16x8*>(qh + col * 32 + gq * 8);
            bl[ni] = *reinterpret_cast<const f16x8*>(ql + col * 32 + gq * 8);
        }
        #pragma unroll
        for (int mi = 0; mi < 2; ++mi)
            #pragma unroll
            for (int ni = 0; ni < 2; ++ni) {
                f32x4 d = {0.f, 0.f, 0.f, 0.f};
                d = __builtin_amdgcn_mfma_f32_16x16x32_f16(sh[mi], bh[ni], d, 0, 0, 0);
                d = __builtin_amdgcn_mfma_f32_16x16x32_f16(sh[mi], bl[ni], d, 0, 0, 0);
                d = __builtin_amdgcn_mfma_f32_16x16x32_f16(sl[mi], bh[ni], d, 0, 0, 0);
                qd[mi][ni] = d;
            }
        __syncthreads();
    }
    const float cf = 0.3486784401f;   // 0.9^10
    #pragma unroll
    for (int mi = 0; mi < 2; ++mi)
        #pragma unroll
        for (int ni = 0; ni < 2; ++ni)
            #pragma unroll
            for (int r = 0; r < 4; ++r) {
                int row = mi * 16 + gq * 4 + r, col = ni * 16 + lr;
                if (row < 30 && col < 30)
                    P[b * 900 + row * 30 + col] = racc[mi][ni][r] + cf * qd[mi][ni][r];
            }
}

// ---------------- k_main ----------------
// block = 4 batches (rows q*32+0..29 valid, q*32+{30,31} zeroed), M=128.
// 512 threads = 8 waves; wave owns 64 feature-cols.
// buf alias: As[128][256] f32 (128K, DMA'd, src-swizzled) -> xl[128][512] f16
//            (128K) -> ut[512][128] f16 (128K)
#define SMEM_BYTES 152576
#define PF_OFF   131072  // Pf [4][32][40] f16 = 10240 (rows padded 32->40 vs bank conflicts)
#define B1L_OFF  141312  // [512] f32
#define B2L_OFF  143360  // [512] f32
#define WLL_OFF  145408  // [512] f32
#define RED_OFF  147456  // [8][128] f32 = 4096
#define VL_OFF   151552  // [128] f32
#define ZL_OFF   152064  // [128] f32

__global__ __launch_bounds__(512, 2) void k_main(
    const float* __restrict__ real, const f16* __restrict__ w1t,
    const f16* __restrict__ w2t, const float* __restrict__ b1,
    const float* __restrict__ b2, const float* __restrict__ wl,
    const float* __restrict__ bl, const float* __restrict__ wc,
    const float* __restrict__ bc, const float* __restrict__ Pws,
    float* __restrict__ out) {
    extern __shared__ char smem[];
    char*  buf = smem;
    f16*   Pf  = (f16*)(smem + PF_OFF);
    float* b1l = (float*)(smem + B1L_OFF);
    float* b2l = (float*)(smem + B2L_OFF);
    float* wll = (float*)(smem + WLL_OFF);
    float* red = (float*)(smem + RED_OFF);
    float* vl  = (float*)(smem + VL_OFF);
    float* zl  = (float*)(smem + ZL_OFF);

    const int tid  = threadIdx.x;
    const int lane = tid & 63;
    const int wv   = tid >> 6;
    const int gq   = lane >> 4;
    const int lr   = lane & 15;
    const int blk  = blockIdx.x;         // 0..1023
    const long r0  = (long)blk * 120;

    // ---- async As staging: one 1KB row per wave-call, 16B/lane DMA ----
    // LDS dest linear (base + lane*16); read-side XOR swizzle ((row&7)<<4) is
    // realized by pre-swizzling the per-lane SOURCE chunk: lane ^ (row&7).
    // row = wv + 8*i  =>  row&7 == wv.
    const float* rbase = real + r0 * 256;
    #pragma unroll
    for (int i = 0; i < 16; ++i) {
        const int row = wv + 8 * i;
        const int rr  = row & 31;
        if (rr < 30) {                    // wave-uniform condition
            const float* gp = rbase + ((long)((row >> 5) * 30 + rr)) * 256
                              + ((lane ^ wv) << 2);
            __builtin_amdgcn_global_load_lds(
                (const __attribute__((address_space(1))) unsigned int*)gp,
                (__attribute__((address_space(3))) unsigned int*)(buf + row * 1024),
                16, 0, 0);
        }
    }
    // zero the 8 pad rows (rr = 30,31 of each batch) — never DMA'd
    {
        const int i   = tid >> 6;                        // 0..7
        const int row = ((i >> 1) << 5) + 30 + (i & 1);  // 30,31,62,63,94,95,126,127
        f32x4 z = {0.f, 0.f, 0.f, 0.f};
        *reinterpret_cast<f32x4*>(buf + row * 1024 + (tid & 63) * 16) = z;
    }
    // ---- Pf [4][32][40] f16 (k-padded to 32 with zeros; row stride 40) ----
    #pragma unroll
    for (int s = 0; s < 8; ++s) {
        int e = tid + s * 512;            // 0..4095
        int bb = e >> 10, idx = e & 1023, n = idx >> 5, kk = idx & 31;
        float p = (n < 30 && kk < 30)
            ? Pws[((long)blk * 4 + bb) * 900 + n * 30 + kk] : 0.f;
        Pf[bb * 1280 + n * 40 + kk] = (f16)p;
    }
    b1l[tid] = b1[tid];
    b2l[tid] = b2[tid];
    wll[tid] = wl[tid];

    f32x4 acc[4][8];
    #pragma unroll
    for (int a = 0; a < 4; ++a)
        #pragma unroll
        for (int b = 0; b < 8; ++b) { f32x4 z = {0.f,0.f,0.f,0.f}; acc[a][b] = z; }
    __syncthreads();                      // drains DMA (vmcnt) + LDS writes

    // ======== GEMM1: D[feat][node] = W1^T @ A^T, K=256 — barrier-free ========
    const f16* w1p = w1t + (wv * 64 + lr) * 256;
    #pragma unroll
    for (int kc = 0; kc < 8; ++kc) {
        f16x8 wa[4];
        #pragma unroll
        for (int mi = 0; mi < 4; ++mi)
            wa[mi] = *reinterpret_cast<const f16x8*>(w1p + mi * 4096 + kc * 32 + gq * 8);
        f16x8 bf[8];
        #pragma unroll
        for (int ni = 0; ni < 8; ++ni) {
            const int row = ni * 16 + lr;
            const int cb  = kc * 128 + gq * 32;
            f32x4 a0 = *reinterpret_cast<const f32x4*>(
                buf + row * 1024 + (cb ^ ((row & 7) << 4)));
            f32x4 a1 = *reinterpret_cast<const f32x4*>(
                buf + row * 1024 + ((cb + 16) ^ ((row & 7) << 4)));
            f16x8 h;
            h[0]=(f16)a0[0]; h[1]=(f16)a0[1]; h[2]=(f16)a0[2]; h[3]=(f16)a0[3];
            h[4]=(f16)a1[0]; h[5]=(f16)a1[1]; h[6]=(f16)a1[2]; h[7]=(f16)a1[3];
            bf[ni] = h;
        }
        __builtin_amdgcn_s_setprio(1);
        #pragma unroll
        for (int mi = 0; mi < 4; ++mi)
            #pragma unroll
            for (int ni = 0; ni < 8; ++ni)
                acc[mi][ni] = __builtin_amdgcn_mfma_f32_16x16x32_f16(wa[mi], bf[ni], acc[mi][ni], 0, 0, 0);
        __builtin_amdgcn_s_setprio(0);
    }
    __syncthreads();   // As reads done; buf -> xl[128][512] f16

    // ---- ep1: xl[node][feat] = relu(acc + b1), b64 writes, (node&15)<<4 swz ----
    #pragma unroll
    for (int mi = 0; mi < 4; ++mi) {
        const int featb = wv * 64 + mi * 16 + gq * 4;
        float b1v[4];
        #pragma unroll
        for (int j = 0; j < 4; ++j) b1v[j] = b1l[featb + j];
        #pragma unroll
        for (int ni = 0; ni < 8; ++ni) {
            const int node = ni * 16 + lr;
            f16x4 h;
            #pragma unroll
            for (int j = 0; j < 4; ++j)
                h[j] = (f16)fmaxf(acc[mi][ni][j] + b1v[j], 0.f);
            *reinterpret_cast<f16x4*>(
                buf + node * 1024 + ((featb * 2) ^ ((node & 15) << 4))) = h;
        }
    }
    #pragma unroll
    for (int a = 0; a < 4; ++a)
        #pragma unroll
        for (int b = 0; b < 8; ++b) { f32x4 z = {0.f,0.f,0.f,0.f}; acc[a][b] = z; }
    __syncthreads();

    // ======== GEMM2: D[node][feat] = x @ W2, K=512 — barrier-free ========
    const f16* w2p = w2t + (wv * 64 + lr) * 512;
    f16x8 bfA[4], bfB[4];
    #pragma unroll
    for (int ni = 0; ni < 4; ++ni)
        bfA[ni] = *reinterpret_cast<const f16x8*>(w2p + ni * 8192 + gq * 8);
    #pragma unroll
    for (int ni = 0; ni < 4; ++ni)
        bfB[ni] = *reinterpret_cast<const f16x8*>(w2p + ni * 8192 + 32 + gq * 8);
    #pragma unroll
    for (int kc2 = 0; kc2 < 8; ++kc2) {
        {   // even kc
            const int kc = 2 * kc2;
            f16x8 af[8];
            #pragma unroll
            for (int mi = 0; mi < 8; ++mi) {
                const int row = mi * 16 + lr;
                af[mi] = *reinterpret_cast<const f16x8*>(
                    buf + row * 1024 + (((kc * 32 + gq * 8) * 2) ^ ((row & 15) << 4)));
            }
            __builtin_amdgcn_s_setprio(1);
            #pragma unroll
            for (int mi = 0; mi < 8; ++mi)
                #pragma unroll
                for (int ni = 0; ni < 4; ++ni)
                    acc[ni][mi] = __builtin_amdgcn_mfma_f32_16x16x32_f16(af[mi], bfA[ni], acc[ni][mi], 0, 0, 0);
            __builtin_amdgcn_s_setprio(0);
            if (kc + 2 < 16)
                #pragma unroll
                for (int ni = 0; ni < 4; ++ni)
                    bfA[ni] = *reinterpret_cast<const f16x8*>(w2p + ni * 8192 + (kc + 2) * 32 + gq * 8);
        }
        {   // odd kc
            const int kc = 2 * kc2 + 1;
            f16x8 af[8];
            #pragma unroll
            for (int mi = 0; mi < 8; ++mi) {
                const int row = mi * 16 + lr;
                af[mi] = *reinterpret_cast<const f16x8*>(
                    buf + row * 1024 + (((kc * 32 + gq * 8) * 2) ^ ((row & 15) << 4)));
            }
            __builtin_amdgcn_s_setprio(1);
            #pragma unroll
            for (int mi = 0; mi < 8; ++mi)
                #pragma unroll
                for (int ni = 0; ni < 4; ++ni)
                    acc[ni][mi] = __builtin_amdgcn_mfma_f32_16x16x32_f16(af[mi], bfB[ni], acc[ni][mi], 0, 0, 0);
            __builtin_amdgcn_s_setprio(0);
            if (kc + 2 < 16)
                #pragma unroll
                for (int ni = 0; ni < 4; ++ni)
                    bfB[ni] = *reinterpret_cast<const f16x8*>(w2p + ni * 8192 + (kc + 2) * 32 + gq * 8);
        }
    }
    __syncthreads();   // xl reads done; buf -> ut[512][128]

    // ---- ep2: ut[feat][node], b64 writes, (feat&15)<<4 swizzle ----
    #pragma unroll
    for (int mi = 0; mi < 8; ++mi)
        #pragma unroll
        for (int ni = 0; ni < 4; ++ni) {
            const int feat  = wv * 64 + ni * 16 + lr;
            const int node0 = mi * 16 + gq * 4;
            f16x4 h;
            #pragma unroll
            for (int j = 0; j < 4; ++j) h[j] = (f16)acc[ni][mi][j];
            *reinterpret_cast<f16x4*>(
                buf + feat * 256 + ((node0 * 2) ^ ((feat & 15) << 4))) = h;
        }
    __syncthreads();

    // ======== phase5: Y^T = U^T @ P^T (per batch), y=relu(+b2), v=y.wl ========
    {
        f16x8 pb[4][2];
        #pragma unroll
        for (int bb = 0; bb < 4; ++bb)
            #pragma unroll
            for (int ni = 0; ni < 2; ++ni)
                pb[bb][ni] = *reinterpret_cast<const f16x8*>(
                    Pf + bb * 1280 + (ni * 16 + lr) * 40 + gq * 8);
        float vacc[4][2];
        #pragma unroll
        for (int bb = 0; bb < 4; ++bb)
            #pragma unroll
            for (int ni = 0; ni < 2; ++ni) vacc[bb][ni] = 0.f;
        #pragma unroll
        for (int mi = 0; mi < 4; ++mi) {
            const int featb = wv * 64 + mi * 16;
            float b2v[4], wlv[4];
            #pragma unroll
            for (int j = 0; j < 4; ++j) {
                b2v[j] = b2l[featb + gq * 4 + j];
                wlv[j] = wll[featb + gq * 4 + j];
            }
            f16x8 au[4];
            #pragma unroll
            for (int bb = 0; bb < 4; ++bb) {
                const int feat = featb + lr;
                au[bb] = *reinterpret_cast<const f16x8*>(
                    buf + feat * 256 + ((bb * 64 + gq * 16) ^ ((feat & 15) << 4)));
            }
            #pragma unroll
            for (int bb = 0; bb < 4; ++bb)
                #pragma unroll
                for (int ni = 0; ni < 2; ++ni) {
                    f32x4 d = {0.f,0.f,0.f,0.f};
                    d = __builtin_amdgcn_mfma_f32_16x16x32_f16(au[bb], pb[bb][ni], d, 0, 0, 0);
                    #pragma unroll
                    for (int j = 0; j < 4; ++j) {
                        float y = fmaxf(d[j] + b2v[j], 0.f);
                        vacc[bb][ni] = fmaf(y, wlv[j], vacc[bb][ni]);
                    }
                }
        }
        #pragma unroll
        for (int bb = 0; bb < 4; ++bb)
            #pragma unroll
            for (int ni = 0; ni < 2; ++ni) {
                float v = vacc[bb][ni];
                v += __shfl_xor(v, 16);
                v += __shfl_xor(v, 32);
                if (lane < 16) red[wv * 128 + bb * 32 + ni * 16 + lr] = v;
            }
    }
    __syncthreads();
    if (tid < 128) {
        float s = 0.f;
        #pragma unroll
        for (int w = 0; w < 8; ++w) s += red[w * 128 + tid];
        vl[tid] = s;
    }
    __syncthreads();
    if (tid < 120) {
        const int bb = tid / 30, n = tid - bb * 30;
        const float* Pr = Pws + ((long)blk * 4 + bb) * 900 + n * 30;
        float z = bl[0];
        #pragma unroll
        for (int j = 0; j < 30; ++j) z = fmaf(Pr[j], vl[bb * 32 + j], z);
        zl[tid] = fmaxf(z, 0.f);
    }
    __syncthreads();
    if (tid < 16) {
        const int bb = tid >> 2, cc = tid & 3;
        float o = bc[cc];
        #pragma unroll
        for (int n = 0; n < 30; ++n) o = fmaf(zl[bb * 30 + n], wc[cc * 30 + n], o);
        out[((long)blk * 4 + bb) * 4 + cc] = o;
    }
}

extern "C" void kernel_launch(void* const* d_in, const int* in_sizes, int n_in,
                              void* d_out, int out_size, void* d_ws, size_t ws_size,
                              hipStream_t stream) {
    const float* real  = (const float*)d_in[0];
    const float* graph = (const float*)d_in[2];
    const float* W1    = (const float*)d_in[3];
    const float* b1    = (const float*)d_in[4];
    const float* W2    = (const float*)d_in[5];
    const float* b2    = (const float*)d_in[6];
    const float* Wl    = (const float*)d_in[7];
    const float* bl    = (const float*)d_in[8];
    const float* Wc    = (const float*)d_in[9];
    const float* bc    = (const float*)d_in[10];
    float* out = (float*)d_out;
    char*  ws  = (char*)d_ws;

    float* Pws = (float*)(ws + P_OFF);
    f16*   w1t = (f16*)(ws + W1T_OFF);
    f16*   w2t = (f16*)(ws + W2T_OFF);

    k_prep<<<1536, 256, 0, stream>>>(W1, W2, w1t, w2t);
    k_prop<<<1024, 256, 0, stream>>>(graph, Pws);
    (void)hipFuncSetAttribute((const void*)k_main,
                              hipFuncAttributeMaxDynamicSharedMemorySize, SMEM_BYTES);
    k_main<<<1024, 512, SMEM_BYTES, stream>>>(real, w1t, w2t, b1, b2, Wl, bl, Wc, bc,
                                              Pws, out);
}